// Round 13
// baseline (821.771 us; speedup 1.0000x reference)
//
#include <hip/hip_runtime.h>
#include <hip/hip_bf16.h>
#include <hip/hip_fp16.h>
#include <math.h>

// GatedAttention R13: LDS-BW attack. conv wave tiles enlarged (MACs/LDS-byte
// scales with MwNw/(Mw+Nw)): conv3 MT=128 NOC=1 (wave 64x64, ratio 8, staging
// halved, 1 block/CU), conv2 NPX=128 (wave 32x64), conv4 MT=128 (wave 64x32).
// flash: packed v_cvt_pk_bf16_f32 via __float22bfloat162_rn (was 4-op manual
// f2bf x16/iter; VALU-bound). Numerics identical (absmax expected 0.0078).

#define PI_F 3.1415926f

typedef __attribute__((ext_vector_type(8))) short short8;
typedef __attribute__((ext_vector_type(4))) float f32x4;
typedef _Float16 half8 __attribute__((ext_vector_type(8)));
typedef __attribute__((ext_vector_type(4))) unsigned short u16x4;
typedef __attribute__((ext_vector_type(8))) unsigned short u16x8;
typedef unsigned short ushort_t;

__device__ __forceinline__ ushort_t f2bf(float x) {
    unsigned u = __float_as_uint(x);
    unsigned r = (u + 0x7FFFu + ((u >> 16) & 1u)) >> 16;
    return (ushort_t)r;
}
__device__ __forceinline__ void split16(float x, ushort_t& h, ushort_t& l) {
    __half hh = __float2half(x);
    h = __half_as_ushort(hh);
    l = __half_as_ushort(__float2half(x - __half2float(hh)));
}
// chunk swizzle: half-offset of 16B chunk c within row r (CSTG=32 halves = 4 chunks)
__device__ __forceinline__ int swz(int r, int c) {
    return ((c ^ r ^ (r >> 2)) & 3) << 3;
}

// ---------------- weight transform: OIHW fp32 -> [ky*kx][oc][ic] fp16 hi/lo --------
__global__ __launch_bounds__(256) void transform_w_k(
    const float* __restrict__ w, ushort_t* __restrict__ Wh, ushort_t* __restrict__ Wl,
    int Cout, int Cin, int KK)
{
    int idx = blockIdx.x * 256 + threadIdx.x;
    int N = Cout * Cin * KK;
    if (idx >= N) return;
    int oc = idx / (Cin * KK);
    int rem = idx - oc * (Cin * KK);
    int ic = rem / KK;
    int t = rem - ic * KK;
    float v = w[idx];
    long dst = ((long)t * Cout + oc) * Cin + ic;
    split16(v, Wh[dst], Wl[dst]);
}

// ------- conv1 weight transform: [32][4][7][7] -> [7 ky][32 oc][32 k=kx*4+ic] ------
__global__ __launch_bounds__(256) void transform_w1_k(
    const float* __restrict__ w, ushort_t* __restrict__ Wh, ushort_t* __restrict__ Wl)
{
    int idx = blockIdx.x * 256 + threadIdx.x;
    if (idx >= 7 * 32 * 32) return;
    int ky = idx / 1024;
    int rem = idx - ky * 1024;
    int oc = rem >> 5;
    int k = rem & 31;
    float v = 0.f;
    if (k < 28) {
        int kx = k >> 2, ic = k & 3;
        v = w[((oc * 4 + ic) * 7 + ky) * 7 + kx];
    }
    split16(v, Wh[idx], Wl[idx]);
}

// ------- prep conv1 input: reflect-pad(3) -> channel-last [8][262][262][4] fp16 h/l
__global__ __launch_bounds__(256) void prep_in_k(
    const float* __restrict__ imgs, const float* __restrict__ masks,
    ushort_t* __restrict__ Xh, ushort_t* __restrict__ Xl)
{
    const int iy = blockIdx.x, b = blockIdx.y;
    int sy = iy - 3; if (sy < 0) sy = -sy; if (sy >= 256) sy = 510 - sy;
    const int rb = sy << 8;
    const float* i0 = imgs + (long)b * 3 * 65536;
    const float* mk = masks + (long)b * 65536;
    for (int x = threadIdx.x; x < 262; x += 256) {
        int sx = x - 3; if (sx < 0) sx = -sx; if (sx >= 256) sx = 510 - sx;
        float v0 = i0[rb + sx], v1 = i0[65536 + rb + sx], v2 = i0[131072 + rb + sx];
        float v3 = mk[rb + sx];
        u16x4 hv, lv;
        ushort_t h, l;
        split16(v0, h, l); hv[0] = h; lv[0] = l;
        split16(v1, h, l); hv[1] = h; lv[1] = l;
        split16(v2, h, l); hv[2] = h; lv[2] = l;
        split16(v3, h, l); hv[3] = h; lv[3] = l;
        long o = ((long)(b * 262 + iy) * 262 + x) * 4;
        *(u16x4*)&Xh[o] = hv;
        *(u16x4*)&Xl[o] = lv;
    }
}

// ------- conv1 MFMA: 32 oc x 64 px per block, K = 7ky x 32(kx*4+ic) -----------
__global__ __launch_bounds__(256) void conv1_mfma_k(
    const ushort_t* __restrict__ Xinh, const ushort_t* __restrict__ Xinl,
    const ushort_t* __restrict__ W1h, const ushort_t* __restrict__ W1l,
    const float* __restrict__ bias,
    ushort_t* __restrict__ Oh, ushort_t* __restrict__ Ol)
{
    const int tid = threadIdx.x, lane = tid & 63, wid = tid >> 6;
    const int wm = wid & 1, wn = wid >> 1, l15 = lane & 15, quad = lane >> 4;
    const int ox0 = blockIdx.x * 64;
    const int oy = blockIdx.y, b = blockIdx.z;
    f32x4 acc[2];
    acc[0] = (f32x4){0.f, 0.f, 0.f, 0.f};
    acc[1] = (f32x4){0.f, 0.f, 0.f, 0.f};
#pragma unroll
    for (int ky = 0; ky < 7; ++ky) {
        long wo = (long)(ky * 32 + wm * 16 + l15) * 32 + quad * 8;
        half8 Ah = *(const half8*)&W1h[wo];
        half8 Al = *(const half8*)&W1l[wo];
        long xrow = ((long)(b * 262 + oy + ky) * 262 + ox0) * 4;
#pragma unroll
        for (int ni = 0; ni < 2; ++ni) {
            long xo = xrow + (wn * 32 + ni * 16 + l15) * 4 + quad * 8;
            half8 Bh = *(const half8*)&Xinh[xo];
            half8 Bl = *(const half8*)&Xinl[xo];
            acc[ni] = __builtin_amdgcn_mfma_f32_16x16x32_f16(Ah, Bh, acc[ni], 0, 0, 0);
            acc[ni] = __builtin_amdgcn_mfma_f32_16x16x32_f16(Al, Bh, acc[ni], 0, 0, 0);
            acc[ni] = __builtin_amdgcn_mfma_f32_16x16x32_f16(Ah, Bl, acc[ni], 0, 0, 0);
        }
    }
    const int ocf = wm * 16 + quad * 4;
    float4 bv = *(const float4*)&bias[ocf];
#pragma unroll
    for (int ni = 0; ni < 2; ++ni) {
        int n = ox0 + wn * 32 + ni * 16 + l15;
        float v0 = fmaxf(acc[ni][0] + bv.x, 0.f);
        float v1 = fmaxf(acc[ni][1] + bv.y, 0.f);
        float v2 = fmaxf(acc[ni][2] + bv.z, 0.f);
        float v3 = fmaxf(acc[ni][3] + bv.w, 0.f);
        long o = ((long)(b * 260 + oy + 2) * 260 + n + 2) * 32 + ocf;
        u16x4 hv, lv;
        ushort_t th, tl;
        split16(v0, th, tl); hv[0] = th; lv[0] = tl;
        split16(v1, th, tl); hv[1] = th; lv[1] = tl;
        split16(v2, th, tl); hv[2] = th; lv[2] = tl;
        split16(v3, th, tl); hv[3] = th; lv[3] = tl;
        *(u16x4*)&Oh[o] = hv;
        *(u16x4*)&Ol[o] = lv;
    }
}

// ------- pad-fill for channel-last reflect-padded buffers ----
__global__ __launch_bounds__(256) void pad_cl_k(
    ushort_t* __restrict__ Xh, ushort_t* __restrict__ Xl,
    int Hp, int Wp, int PAD, int C, int H, int W)
{
    const int iy = blockIdx.x, b = blockIdx.y;
    int t = iy - PAD; if (t < 0) t = -t; if (t >= H) t = 2 * H - 2 - t;
    const int iys = t + PAD;
    const long rowd = ((long)(b * Hp + iy) * Wp) * C;
    const long rows = ((long)(b * Hp + iys) * Wp) * C;
    const int nch = Wp * (C >> 3);
    for (int idx = threadIdx.x; idx < nch; idx += 256) {
        int x = idx / (C >> 3);
        int cg = (idx - x * (C >> 3)) << 3;
        int t2 = x - PAD; if (t2 < 0) t2 = -t2; if (t2 >= W) t2 = 2 * W - 2 - t2;
        int xs = t2 + PAD;
        if (xs == x && iys == iy) continue;
        *(int4*)&Xh[rowd + (long)x * C + cg] = *(const int4*)&Xh[rows + (long)xs * C + cg];
        *(int4*)&Xl[rowd + (long)x * C + cg] = *(const int4*)&Xl[rows + (long)xs * C + cg];
    }
}

// ------- MFMA conv (split-fp16), swizzled LDS, de-interleaved columns for S=2 ----
template<int K, int S, int CIN, int CSTG, int MT, int NPX, bool WRITE_CL>
__global__ __launch_bounds__(256, 2) void conv_mfma_k(
    const ushort_t* __restrict__ Xh, const ushort_t* __restrict__ Xl,
    const ushort_t* __restrict__ Wh, const ushort_t* __restrict__ Wl,
    const float* __restrict__ bias,
    int Hp, int Wp, int CoutT,
    ushort_t* __restrict__ Oh, ushort_t* __restrict__ Ol, int Hpn, int Wpn, int NP,
    float* __restrict__ Ofp)
{
    constexpr int WS = (NPX - 1) * S + K;
    constexpr int WS2 = (WS + 1) / 2;
    constexpr int MF = MT / 32;
    constexpr int NF = NPX / 32;
    __shared__ ushort_t Bsh[WS * CSTG];
    __shared__ ushort_t Bsl[WS * CSTG];
    __shared__ ushort_t Ash[K * MT * CSTG];
    __shared__ ushort_t Asl[K * MT * CSTG];
    const int tid = threadIdx.x, lane = tid & 63, wid = tid >> 6;
    const int wm = wid & 1, wn = wid >> 1, l15 = lane & 15, quad = lane >> 4;
    const int bx = blockIdx.x, oy = blockIdx.y;
    const int NOC = CoutT / MT;
    const int ocg = blockIdx.z % NOC, b = blockIdx.z / NOC;
    const int ox0 = bx * NPX;

    f32x4 acc[MF][NF];
#pragma unroll
    for (int mi = 0; mi < MF; ++mi)
#pragma unroll
        for (int ni = 0; ni < NF; ++ni) acc[mi][ni] = (f32x4){0.f, 0.f, 0.f, 0.f};

#pragma unroll
    for (int ky = 0; ky < K; ++ky) {
        const long rowoff = ((long)(b * Hp + oy * S + ky) * Wp + ox0 * S) * CIN;
        for (int cs = 0; cs < CIN; cs += CSTG) {
            __syncthreads();
            constexpr int NCH = WS * CSTG / 8;
#pragma unroll
            for (int it = 0; it < (NCH + 255) / 256; ++it) {
                int flat = tid + it * 256;
                if (flat < NCH) {
                    int e0 = flat * 8;
                    int x = e0 / CSTG;
                    int cpos = (e0 - x * CSTG) >> 3;
                    int xs = (S == 1) ? x : ((x >> 1) + (x & 1) * WS2);
                    int dst = xs * CSTG + swz(xs, cpos);
                    long src = rowoff + (long)x * CIN + cs + cpos * 8;
                    *(int4*)&Bsh[dst] = *(const int4*)&Xh[src];
                    *(int4*)&Bsl[dst] = *(const int4*)&Xl[src];
                }
            }
            constexpr int NW = K * MT * CSTG / 8;
#pragma unroll
            for (int it = 0; it < (NW + 255) / 256; ++it) {
                int flat = tid + it * 256;
                if (flat < NW) {
                    int e0 = flat * 8;
                    int kx = e0 / (MT * CSTG);
                    int rem = e0 - kx * MT * CSTG;
                    int oc = rem / CSTG;
                    int cpos = (rem - oc * CSTG) >> 3;
                    int arow = kx * MT + oc;
                    int dst = arow * CSTG + swz(arow, cpos);
                    long src = ((long)((ky * K + kx) * CoutT + ocg * MT + oc)) * CIN + cs + cpos * 8;
                    *(int4*)&Ash[dst] = *(const int4*)&Wh[src];
                    *(int4*)&Asl[dst] = *(const int4*)&Wl[src];
                }
            }
            __syncthreads();
#pragma unroll
            for (int kx = 0; kx < K; ++kx) {
                half8 Ah[MF], Al[MF], Bh[NF], Bl[NF];
#pragma unroll
                for (int mi = 0; mi < MF; ++mi) {
                    int arow = kx * MT + wm * (MT / 2) + mi * 16 + l15;
                    int ao = arow * CSTG + swz(arow, quad);
                    Ah[mi] = *(const half8*)&Ash[ao];
                    Al[mi] = *(const half8*)&Asl[ao];
                }
#pragma unroll
                for (int ni = 0; ni < NF; ++ni) {
                    int m = wn * (NPX / 2) + ni * 16 + l15;
                    int xs = (S == 1) ? (m + kx) : (m + (kx >> 1) + (kx & 1) * WS2);
                    int bo = xs * CSTG + swz(xs, quad);
                    Bh[ni] = *(const half8*)&Bsh[bo];
                    Bl[ni] = *(const half8*)&Bsl[bo];
                }
#pragma unroll
                for (int mi = 0; mi < MF; ++mi)
#pragma unroll
                    for (int ni = 0; ni < NF; ++ni) {
                        acc[mi][ni] = __builtin_amdgcn_mfma_f32_16x16x32_f16(Ah[mi], Bh[ni], acc[mi][ni], 0, 0, 0);
                        acc[mi][ni] = __builtin_amdgcn_mfma_f32_16x16x32_f16(Al[mi], Bh[ni], acc[mi][ni], 0, 0, 0);
                        acc[mi][ni] = __builtin_amdgcn_mfma_f32_16x16x32_f16(Ah[mi], Bl[ni], acc[mi][ni], 0, 0, 0);
                    }
            }
        }
    }
#pragma unroll
    for (int ni = 0; ni < NF; ++ni) {
        const int n = ox0 + wn * (NPX / 2) + ni * 16 + l15;
#pragma unroll
        for (int mi = 0; mi < MF; ++mi) {
            const int ocf = ocg * MT + wm * (MT / 2) + mi * 16 + quad * 4;
            float4 bv = *(const float4*)&bias[ocf];
            float v0 = fmaxf(acc[mi][ni][0] + bv.x, 0.f);
            float v1 = fmaxf(acc[mi][ni][1] + bv.y, 0.f);
            float v2 = fmaxf(acc[mi][ni][2] + bv.z, 0.f);
            float v3 = fmaxf(acc[mi][ni][3] + bv.w, 0.f);
            if (WRITE_CL) {
                long o = ((long)(b * Hpn + oy + NP) * Wpn + n + NP) * CoutT + ocf;
                u16x4 hv, lv;
                ushort_t th, tl;
                split16(v0, th, tl); hv[0] = th; lv[0] = tl;
                split16(v1, th, tl); hv[1] = th; lv[1] = tl;
                split16(v2, th, tl); hv[2] = th; lv[2] = tl;
                split16(v3, th, tl); hv[3] = th; lv[3] = tl;
                *(u16x4*)&Oh[o] = hv;
                *(u16x4*)&Ol[o] = lv;
            } else {
                long o = ((long)(b * CoutT + ocf) << 12) + (oy << 6) + n;
                Ofp[o] = v0;
                Ofp[o + 4096] = v1;
                Ofp[o + 8192] = v2;
                Ofp[o + 12288] = v3;
            }
        }
    }
}

// -------- conv5 (256->1, K3 S1 P1) + relu + gate ----------
__global__ __launch_bounds__(256) void conv5_gate_k(
    const float* __restrict__ s4, const float* __restrict__ w,
    const float* __restrict__ bias, float* __restrict__ gate)
{
    const int tid = threadIdx.x;
    const int lane = tid & 63, g = tid >> 6;
    const int oy = blockIdx.x, b = blockIdx.y;
    int ixo[3], iyo[3];
#pragma unroll
    for (int k = 0; k < 3; ++k) {
        int ix = lane + k - 1; if (ix < 0) ix = -ix; if (ix >= 64) ix = 126 - ix;
        int iy = oy + k - 1; if (iy < 0) iy = -iy; if (iy >= 64) iy = 126 - iy;
        ixo[k] = ix; iyo[k] = iy << 6;
    }
    float part = 0.f;
    const float* inb = s4 + ((long)b * 256 + g * 64) * 4096;
    const float* wg = w + g * 64 * 9;
    for (int ic = 0; ic < 64; ++ic) {
        const float* inc = inb + ic * 4096;
        const float* wc = wg + ic * 9;
#pragma unroll
        for (int ky = 0; ky < 3; ++ky)
#pragma unroll
            for (int kx = 0; kx < 3; ++kx)
                part = fmaf(wc[ky * 3 + kx], inc[iyo[ky] + ixo[kx]], part);
    }
    __shared__ float red[4][64];
    red[g][lane] = part;
    __syncthreads();
    if (tid < 64) {
        float s = bias[0] + red[0][tid] + red[1][tid] + red[2][tid] + red[3][tid];
        s = fmaxf(s, 0.f);
        gate[(b << 12) + (oy << 6) + tid] = tanf(PI_F * (tanhf(s) - 0.5f));
    }
}

// ---------------- invn[b][p] = 1/sqrt(sum_c (F+1e-7)^2) ----------------
__global__ __launch_bounds__(256) void invn_k(const float* __restrict__ F, float* __restrict__ invn)
{
    const int p = blockIdx.x * 256 + threadIdx.x;
    const int b = blockIdx.y;
    const float* Fb = F + (long)b * 524288;
    float ss = 0.f;
#pragma unroll 8
    for (int c = 0; c < 128; ++c) {
        float v = Fb[c * 4096 + p] + 1e-7f;
        ss = fmaf(v, v, ss);
    }
    invn[(b << 12) + p] = 1.0f / sqrtf(ss);
}

// -------- prep: Fo16[b][c][p] = bf16(F), Ft16[b][p][c] = bf16(F^T) ---------------
__global__ __launch_bounds__(256) void prep_bf16_k(
    const float* __restrict__ F, ushort_t* __restrict__ Fo16, ushort_t* __restrict__ Ft16)
{
    __shared__ float Ls[128][65];
    const int tid = threadIdx.x;
    const int lane = tid & 63, wv = tid >> 6;
    const int p0 = blockIdx.x * 64, b = blockIdx.y;
#pragma unroll 8
    for (int cc = 0; cc < 32; ++cc) {
        int c = wv * 32 + cc;
        long idx = ((long)b * 128 + c) * 4096 + p0 + lane;
        float v = F[idx];
        Fo16[idx] = f2bf(v);
        Ls[c][lane] = v;
    }
    __syncthreads();
#pragma unroll 8
    for (int i = 0; i < 32; ++i) {
        int flat = tid + 256 * i;
        int c = flat & 127, pl_ = flat >> 7;
        Ft16[((long)b * 4096 + p0 + pl_) * 128 + c] = f2bf(Ls[c][pl_]);
    }
}

// -------- flash attention: no max-subtraction, packed bf16 convert ---------------
__global__ __launch_bounds__(256) void flash_attn_k(
    const ushort_t* __restrict__ Ft16, const ushort_t* __restrict__ Fo16,
    const float* __restrict__ invn, const float* __restrict__ gate,
    float* __restrict__ Opart, float* __restrict__ lpart)
{
    __shared__ float redS[64][4];
    __shared__ ushort_t Es[64][72];
    const int tid = threadIdx.x, lane = tid & 63, w = tid >> 6;
    const int l15 = lane & 15, quad = lane >> 4;
    const int q0 = blockIdx.x * 64;
    const int ks = blockIdx.y, b = blockIdx.z;
    const int bp = b << 12;
    const ushort_t* Ftb = Ft16 + (long)b * 4096 * 128;
    const ushort_t* Fob = Fo16 + (long)b * 128 * 4096;

    short8 Bq[4][4];
#pragma unroll
    for (int ni = 0; ni < 4; ++ni)
#pragma unroll
        for (int cs = 0; cs < 4; ++cs)
            Bq[ni][cs] = *(const short8*)&Ftb[(long)(q0 + ni * 16 + l15) * 128 + cs * 32 + quad * 8];

    f32x4 O[2][4];
#pragma unroll
    for (int mi = 0; mi < 2; ++mi)
#pragma unroll
        for (int ni = 0; ni < 4; ++ni) O[mi][ni] = (f32x4){0.f, 0.f, 0.f, 0.f};
    float l_acc[4] = {0.f, 0.f, 0.f, 0.f};

    const int p_beg = ks * 2048;
    for (int p0 = p_beg; p0 < p_beg + 2048; p0 += 64) {
        f32x4 Sa[4];
#pragma unroll
        for (int ni = 0; ni < 4; ++ni) Sa[ni] = (f32x4){0.f, 0.f, 0.f, 0.f};
#pragma unroll
        for (int cs = 0; cs < 4; ++cs) {
            short8 Ap = *(const short8*)&Ftb[(long)(p0 + w * 16 + l15) * 128 + cs * 32 + quad * 8];
#pragma unroll
            for (int ni = 0; ni < 4; ++ni)
                Sa[ni] = __builtin_amdgcn_mfma_f32_16x16x32_bf16(Ap, Bq[ni][cs], Sa[ni], 0, 0, 0);
        }
        float4 iv = *(const float4*)&invn[bp + p0 + w * 16 + quad * 4];
        float4 gt = *(const float4*)&gate[bp + p0 + w * 16 + quad * 4];
#pragma unroll
        for (int ni = 0; ni < 4; ++ni) {
            float e0 = __expf(fmaf(Sa[ni][0], iv.x, gt.x));
            float e1 = __expf(fmaf(Sa[ni][1], iv.y, gt.y));
            float e2 = __expf(fmaf(Sa[ni][2], iv.z, gt.z));
            float e3 = __expf(fmaf(Sa[ni][3], iv.w, gt.w));
            union { u16x4 v; __hip_bfloat162 h[2]; } u;
            u.h[0] = __float22bfloat162_rn(make_float2(e0, e1));
            u.h[1] = __float22bfloat162_rn(make_float2(e2, e3));
            *(u16x4*)&Es[ni * 16 + l15][w * 16 + quad * 4] = u.v;
            l_acc[ni] += (e0 + e1) + (e2 + e3);
        }
        __syncthreads();
#pragma unroll
        for (int ksub = 0; ksub < 2; ++ksub) {
            short8 Ac[2], Be[4];
#pragma unroll
            for (int mi = 0; mi < 2; ++mi)
                Ac[mi] = *(const short8*)&Fob[(long)(w * 32 + mi * 16 + l15) * 4096 + p0 + ksub * 32 + quad * 8];
#pragma unroll
            for (int ni = 0; ni < 4; ++ni)
                Be[ni] = *(const short8*)&Es[ni * 16 + l15][ksub * 32 + quad * 8];
#pragma unroll
            for (int mi = 0; mi < 2; ++mi)
#pragma unroll
                for (int ni = 0; ni < 4; ++ni)
                    O[mi][ni] = __builtin_amdgcn_mfma_f32_16x16x32_bf16(Ac[mi], Be[ni], O[mi][ni], 0, 0, 0);
        }
        __syncthreads();
    }
#pragma unroll
    for (int ni = 0; ni < 4; ++ni) {
        float lt = l_acc[ni];
        lt += __shfl_xor(lt, 16);
        lt += __shfl_xor(lt, 32);
        if (quad == 0) redS[ni * 16 + l15][w] = lt;
    }
    __syncthreads();
    if (w == 0 && quad == 0) {
#pragma unroll
        for (int ni = 0; ni < 4; ++ni) {
            int q = q0 + ni * 16 + l15;
            float4 rs = *(const float4*)&redS[ni * 16 + l15][0];
            lpart[(ks * 8 + b) * 4096 + q] = (rs.x + rs.y) + (rs.z + rs.w);
        }
    }
    float* Ob = Opart + (long)(ks * 8 + b) * 524288;
#pragma unroll
    for (int mi = 0; mi < 2; ++mi)
#pragma unroll
        for (int ni = 0; ni < 4; ++ni) {
            int c = w * 32 + mi * 16 + quad * 4;
            int q = q0 + ni * 16 + l15;
#pragma unroll
            for (int r = 0; r < 4; ++r)
                Ob[((long)(c + r) << 12) + q] = O[mi][ni][r];
        }
}

// ---------------- combiner: merge split-K, out = cwA*(O/l) + cwF*F + cb ----------
__global__ __launch_bounds__(256) void combiner_k(
    const float* __restrict__ Opart, const float* __restrict__ lpart,
    const float* __restrict__ F, const float* __restrict__ cw,
    const float* __restrict__ cb, float* __restrict__ out)
{
    const int tid = threadIdx.x;
    const int q = blockIdx.x * 256 + tid;
    const int o0 = blockIdx.y << 4;
    const int b = blockIdx.z;
    float il = 1.0f / (lpart[b * 4096 + q] + lpart[(8 + b) * 4096 + q]);
    const float* A0 = Opart + (long)b * 524288 + q;
    const float* A1 = Opart + (long)(8 + b) * 524288 + q;
    const float* Fb = F + (long)b * 524288 + q;
    float acc[16];
#pragma unroll
    for (int j = 0; j < 16; ++j) acc[j] = cb[o0 + j];
    for (int c = 0; c < 128; ++c) {
        float a = (A0[(long)c * 4096] + A1[(long)c * 4096]) * il;
        float f = Fb[(long)c * 4096];
#pragma unroll
        for (int j = 0; j < 16; ++j) {
            acc[j] = fmaf(cw[(o0 + j) * 256 + c], a, acc[j]);
            acc[j] = fmaf(cw[(o0 + j) * 256 + 128 + c], f, acc[j]);
        }
    }
#pragma unroll
    for (int j = 0; j < 16; ++j)
        out[((long)(b * 128 + o0 + j) << 12) + q] = acc[j];
}

// =====================================================================================
extern "C" void kernel_launch(void* const* d_in, const int* in_sizes, int n_in,
                              void* d_out, int out_size, void* d_ws, size_t ws_size,
                              hipStream_t stream)
{
    const float* F     = (const float*)d_in[0];
    const float* imgs  = (const float*)d_in[1];
    const float* masks = (const float*)d_in[2];
    const float* gw1 = (const float*)d_in[3];  const float* gb1 = (const float*)d_in[4];
    const float* gw2 = (const float*)d_in[5];  const float* gb2 = (const float*)d_in[6];
    const float* gw3 = (const float*)d_in[7];  const float* gb3 = (const float*)d_in[8];
    const float* gw4 = (const float*)d_in[9];  const float* gb4 = (const float*)d_in[10];
    const float* gw5 = (const float*)d_in[11]; const float* gb5 = (const float*)d_in[12];
    const float* cw  = (const float*)d_in[13]; const float* cb  = (const float*)d_in[14];
    float* out = (float*)d_out;

    // ---- workspace layout (float offsets), ~150 MB ----
    float* W = (float*)d_ws;
    ushort_t* Xcl2h = (ushort_t*)(W);                 // [8][260][260][32] fp16
    ushort_t* Xcl2l = (ushort_t*)(W + 8652800);
    ushort_t* Xcl4h = (ushort_t*)(W);                 // [8][130][130][128] fp16
    ushort_t* Xcl4l = (ushort_t*)(W + 8652800);
    float*    Opart = W;                              // [2][8][128][4096] f32
    float*    lpart = W + 8388608;                    // [2][8][4096]
    ushort_t* Xcl3h = (ushort_t*)(W + 17305600);      // [8][132][132][64] fp16
    ushort_t* Xcl3l = (ushort_t*)(W + 21766144);
    ushort_t* Fo16  = (ushort_t*)(W + 17305600);      // [8][128][4096] bf16 (after conv3)
    float*    s4   = W + 26226688;                    // [8][256][64][64] f32
    ushort_t* Ft16 = (ushort_t*)(W + 30420992);       // [8][4096][128] bf16 (after conv5)
    ushort_t* W2h = (ushort_t*)(W + 34615296);
    ushort_t* W2l = (ushort_t*)(W + 34640896);
    ushort_t* W3h = (ushort_t*)(W + 34666496);
    ushort_t* W3l = (ushort_t*)(W + 34768896);
    ushort_t* W4h = (ushort_t*)(W + 34871296);
    ushort_t* W4l = (ushort_t*)(W + 35018752);
    float* gate = W + 35166208;
    float* invn = W + 35198976;
    ushort_t* Xinh = (ushort_t*)(W + 35231744);       // [8][262][262][4] fp16 + slack
    ushort_t* Xinl = (ushort_t*)(W + 36330080);
    ushort_t* W1h  = (ushort_t*)(W + 37428416);       // [7][32][32] fp16
    ushort_t* W1l  = (ushort_t*)(W + 37432000);

    // ---- weight transforms + conv1 input prep ----
    transform_w_k<<<dim3(200),  256, 0, stream>>>(gw2, W2h, W2l, 64, 32, 25);
    transform_w_k<<<dim3(800),  256, 0, stream>>>(gw3, W3h, W3l, 128, 64, 25);
    transform_w_k<<<dim3(1152), 256, 0, stream>>>(gw4, W4h, W4l, 256, 128, 9);
    transform_w1_k<<<dim3(28), 256, 0, stream>>>(gw1, W1h, W1l);
    prep_in_k<<<dim3(262, 8), 256, 0, stream>>>(imgs, masks, Xinh, Xinl);

    // ---- conv stack ----
    conv1_mfma_k<<<dim3(4, 256, 8), 256, 0, stream>>>(Xinh, Xinl, W1h, W1l, gb1, Xcl2h, Xcl2l);
    pad_cl_k<<<dim3(260, 8), 256, 0, stream>>>(Xcl2h, Xcl2l, 260, 260, 2, 32, 256, 256);
    // conv2: wave 32x64 (NPX=128)
    conv_mfma_k<5, 2, 32, 32, 64, 128, true><<<dim3(1, 128, 8), 256, 0, stream>>>(
        Xcl2h, Xcl2l, W2h, W2l, gb2, 260, 260, 64, Xcl3h, Xcl3l, 132, 132, 2, nullptr);
    pad_cl_k<<<dim3(132, 8), 256, 0, stream>>>(Xcl3h, Xcl3l, 132, 132, 2, 64, 128, 128);
    // conv3: MT=128 NOC=1, wave 64x64 (ratio 8 MACs/B, staging halved)
    conv_mfma_k<5, 1, 64, 32, 128, 128, true><<<dim3(1, 128, 8), 256, 0, stream>>>(
        Xcl3h, Xcl3l, W3h, W3l, gb3, 132, 132, 128, Xcl4h, Xcl4l, 130, 130, 1, nullptr);
    pad_cl_k<<<dim3(130, 8), 256, 0, stream>>>(Xcl4h, Xcl4l, 130, 130, 1, 128, 128, 128);
    // conv4: MT=128 NOC=2, wave 64x32
    conv_mfma_k<3, 2, 128, 32, 128, 64, false><<<dim3(1, 64, 16), 256, 0, stream>>>(
        Xcl4h, Xcl4l, W4h, W4l, gb4, 130, 130, 256, nullptr, nullptr, 0, 0, 0, s4);
    conv5_gate_k<<<dim3(64, 8), 256, 0, stream>>>(s4, gw5, gb5, gate);

    // ---- attention ----
    invn_k<<<dim3(16, 8), 256, 0, stream>>>(F, invn);
    prep_bf16_k<<<dim3(64, 8), 256, 0, stream>>>(F, Fo16, Ft16);
    flash_attn_k<<<dim3(64, 2, 8), 256, 0, stream>>>(Ft16, Fo16, invn, gate, Opart, lpart);
    combiner_k<<<dim3(16, 8, 8), 256, 0, stream>>>(Opart, lpart, F, cw, cb, out);
}

// Round 14
// 764.714 us; speedup vs baseline: 1.0746x; 1.0746x over previous
//
#include <hip/hip_runtime.h>
#include <hip/hip_bf16.h>
#include <hip/hip_fp16.h>
#include <math.h>

// GatedAttention R14: conv3 reverted to R12 tile (MT=64,NPX=128: 2 blocks/CU beat
// R13's bigger tile at 1 block/CU). Flash: double-buffered Es -> 1 barrier/iter
// (WAR-safe via per-wave program order), split-K=4 (2048 blocks). conv2/conv4
// keep R13 tiles (2 blocks/CU). Numerics identical (absmax expected 0.0078).

#define PI_F 3.1415926f

typedef __attribute__((ext_vector_type(8))) short short8;
typedef __attribute__((ext_vector_type(4))) float f32x4;
typedef _Float16 half8 __attribute__((ext_vector_type(8)));
typedef __attribute__((ext_vector_type(4))) unsigned short u16x4;
typedef __attribute__((ext_vector_type(8))) unsigned short u16x8;
typedef unsigned short ushort_t;

__device__ __forceinline__ ushort_t f2bf(float x) {
    unsigned u = __float_as_uint(x);
    unsigned r = (u + 0x7FFFu + ((u >> 16) & 1u)) >> 16;
    return (ushort_t)r;
}
__device__ __forceinline__ void split16(float x, ushort_t& h, ushort_t& l) {
    __half hh = __float2half(x);
    h = __half_as_ushort(hh);
    l = __half_as_ushort(__float2half(x - __half2float(hh)));
}
__device__ __forceinline__ int swz(int r, int c) {
    return ((c ^ r ^ (r >> 2)) & 3) << 3;
}

// ---------------- weight transform: OIHW fp32 -> [ky*kx][oc][ic] fp16 hi/lo --------
__global__ __launch_bounds__(256) void transform_w_k(
    const float* __restrict__ w, ushort_t* __restrict__ Wh, ushort_t* __restrict__ Wl,
    int Cout, int Cin, int KK)
{
    int idx = blockIdx.x * 256 + threadIdx.x;
    int N = Cout * Cin * KK;
    if (idx >= N) return;
    int oc = idx / (Cin * KK);
    int rem = idx - oc * (Cin * KK);
    int ic = rem / KK;
    int t = rem - ic * KK;
    float v = w[idx];
    long dst = ((long)t * Cout + oc) * Cin + ic;
    split16(v, Wh[dst], Wl[dst]);
}

// ------- conv1 weight transform: [32][4][7][7] -> [7 ky][32 oc][32 k=kx*4+ic] ------
__global__ __launch_bounds__(256) void transform_w1_k(
    const float* __restrict__ w, ushort_t* __restrict__ Wh, ushort_t* __restrict__ Wl)
{
    int idx = blockIdx.x * 256 + threadIdx.x;
    if (idx >= 7 * 32 * 32) return;
    int ky = idx / 1024;
    int rem = idx - ky * 1024;
    int oc = rem >> 5;
    int k = rem & 31;
    float v = 0.f;
    if (k < 28) {
        int kx = k >> 2, ic = k & 3;
        v = w[((oc * 4 + ic) * 7 + ky) * 7 + kx];
    }
    split16(v, Wh[idx], Wl[idx]);
}

// ------- prep conv1 input: reflect-pad(3) -> channel-last [8][262][262][4] fp16 h/l
__global__ __launch_bounds__(256) void prep_in_k(
    const float* __restrict__ imgs, const float* __restrict__ masks,
    ushort_t* __restrict__ Xh, ushort_t* __restrict__ Xl)
{
    const int iy = blockIdx.x, b = blockIdx.y;
    int sy = iy - 3; if (sy < 0) sy = -sy; if (sy >= 256) sy = 510 - sy;
    const int rb = sy << 8;
    const float* i0 = imgs + (long)b * 3 * 65536;
    const float* mk = masks + (long)b * 65536;
    for (int x = threadIdx.x; x < 262; x += 256) {
        int sx = x - 3; if (sx < 0) sx = -sx; if (sx >= 256) sx = 510 - sx;
        float v0 = i0[rb + sx], v1 = i0[65536 + rb + sx], v2 = i0[131072 + rb + sx];
        float v3 = mk[rb + sx];
        u16x4 hv, lv;
        ushort_t h, l;
        split16(v0, h, l); hv[0] = h; lv[0] = l;
        split16(v1, h, l); hv[1] = h; lv[1] = l;
        split16(v2, h, l); hv[2] = h; lv[2] = l;
        split16(v3, h, l); hv[3] = h; lv[3] = l;
        long o = ((long)(b * 262 + iy) * 262 + x) * 4;
        *(u16x4*)&Xh[o] = hv;
        *(u16x4*)&Xl[o] = lv;
    }
}

// ------- conv1 MFMA: 32 oc x 64 px per block, K = 7ky x 32(kx*4+ic) -----------
__global__ __launch_bounds__(256) void conv1_mfma_k(
    const ushort_t* __restrict__ Xinh, const ushort_t* __restrict__ Xinl,
    const ushort_t* __restrict__ W1h, const ushort_t* __restrict__ W1l,
    const float* __restrict__ bias,
    ushort_t* __restrict__ Oh, ushort_t* __restrict__ Ol)
{
    const int tid = threadIdx.x, lane = tid & 63, wid = tid >> 6;
    const int wm = wid & 1, wn = wid >> 1, l15 = lane & 15, quad = lane >> 4;
    const int ox0 = blockIdx.x * 64;
    const int oy = blockIdx.y, b = blockIdx.z;
    f32x4 acc[2];
    acc[0] = (f32x4){0.f, 0.f, 0.f, 0.f};
    acc[1] = (f32x4){0.f, 0.f, 0.f, 0.f};
#pragma unroll
    for (int ky = 0; ky < 7; ++ky) {
        long wo = (long)(ky * 32 + wm * 16 + l15) * 32 + quad * 8;
        half8 Ah = *(const half8*)&W1h[wo];
        half8 Al = *(const half8*)&W1l[wo];
        long xrow = ((long)(b * 262 + oy + ky) * 262 + ox0) * 4;
#pragma unroll
        for (int ni = 0; ni < 2; ++ni) {
            long xo = xrow + (wn * 32 + ni * 16 + l15) * 4 + quad * 8;
            half8 Bh = *(const half8*)&Xinh[xo];
            half8 Bl = *(const half8*)&Xinl[xo];
            acc[ni] = __builtin_amdgcn_mfma_f32_16x16x32_f16(Ah, Bh, acc[ni], 0, 0, 0);
            acc[ni] = __builtin_amdgcn_mfma_f32_16x16x32_f16(Al, Bh, acc[ni], 0, 0, 0);
            acc[ni] = __builtin_amdgcn_mfma_f32_16x16x32_f16(Ah, Bl, acc[ni], 0, 0, 0);
        }
    }
    const int ocf = wm * 16 + quad * 4;
    float4 bv = *(const float4*)&bias[ocf];
#pragma unroll
    for (int ni = 0; ni < 2; ++ni) {
        int n = ox0 + wn * 32 + ni * 16 + l15;
        float v0 = fmaxf(acc[ni][0] + bv.x, 0.f);
        float v1 = fmaxf(acc[ni][1] + bv.y, 0.f);
        float v2 = fmaxf(acc[ni][2] + bv.z, 0.f);
        float v3 = fmaxf(acc[ni][3] + bv.w, 0.f);
        long o = ((long)(b * 260 + oy + 2) * 260 + n + 2) * 32 + ocf;
        u16x4 hv, lv;
        ushort_t th, tl;
        split16(v0, th, tl); hv[0] = th; lv[0] = tl;
        split16(v1, th, tl); hv[1] = th; lv[1] = tl;
        split16(v2, th, tl); hv[2] = th; lv[2] = tl;
        split16(v3, th, tl); hv[3] = th; lv[3] = tl;
        *(u16x4*)&Oh[o] = hv;
        *(u16x4*)&Ol[o] = lv;
    }
}

// ------- pad-fill for channel-last reflect-padded buffers ----
__global__ __launch_bounds__(256) void pad_cl_k(
    ushort_t* __restrict__ Xh, ushort_t* __restrict__ Xl,
    int Hp, int Wp, int PAD, int C, int H, int W)
{
    const int iy = blockIdx.x, b = blockIdx.y;
    int t = iy - PAD; if (t < 0) t = -t; if (t >= H) t = 2 * H - 2 - t;
    const int iys = t + PAD;
    const long rowd = ((long)(b * Hp + iy) * Wp) * C;
    const long rows = ((long)(b * Hp + iys) * Wp) * C;
    const int nch = Wp * (C >> 3);
    for (int idx = threadIdx.x; idx < nch; idx += 256) {
        int x = idx / (C >> 3);
        int cg = (idx - x * (C >> 3)) << 3;
        int t2 = x - PAD; if (t2 < 0) t2 = -t2; if (t2 >= W) t2 = 2 * W - 2 - t2;
        int xs = t2 + PAD;
        if (xs == x && iys == iy) continue;
        *(int4*)&Xh[rowd + (long)x * C + cg] = *(const int4*)&Xh[rows + (long)xs * C + cg];
        *(int4*)&Xl[rowd + (long)x * C + cg] = *(const int4*)&Xl[rows + (long)xs * C + cg];
    }
}

// ------- MFMA conv (split-fp16), swizzled LDS, de-interleaved columns for S=2 ----
template<int K, int S, int CIN, int CSTG, int MT, int NPX, bool WRITE_CL>
__global__ __launch_bounds__(256, 2) void conv_mfma_k(
    const ushort_t* __restrict__ Xh, const ushort_t* __restrict__ Xl,
    const ushort_t* __restrict__ Wh, const ushort_t* __restrict__ Wl,
    const float* __restrict__ bias,
    int Hp, int Wp, int CoutT,
    ushort_t* __restrict__ Oh, ushort_t* __restrict__ Ol, int Hpn, int Wpn, int NP,
    float* __restrict__ Ofp)
{
    constexpr int WS = (NPX - 1) * S + K;
    constexpr int WS2 = (WS + 1) / 2;
    constexpr int MF = MT / 32;
    constexpr int NF = NPX / 32;
    __shared__ ushort_t Bsh[WS * CSTG];
    __shared__ ushort_t Bsl[WS * CSTG];
    __shared__ ushort_t Ash[K * MT * CSTG];
    __shared__ ushort_t Asl[K * MT * CSTG];
    const int tid = threadIdx.x, lane = tid & 63, wid = tid >> 6;
    const int wm = wid & 1, wn = wid >> 1, l15 = lane & 15, quad = lane >> 4;
    const int bx = blockIdx.x, oy = blockIdx.y;
    const int NOC = CoutT / MT;
    const int ocg = blockIdx.z % NOC, b = blockIdx.z / NOC;
    const int ox0 = bx * NPX;

    f32x4 acc[MF][NF];
#pragma unroll
    for (int mi = 0; mi < MF; ++mi)
#pragma unroll
        for (int ni = 0; ni < NF; ++ni) acc[mi][ni] = (f32x4){0.f, 0.f, 0.f, 0.f};

#pragma unroll
    for (int ky = 0; ky < K; ++ky) {
        const long rowoff = ((long)(b * Hp + oy * S + ky) * Wp + ox0 * S) * CIN;
        for (int cs = 0; cs < CIN; cs += CSTG) {
            __syncthreads();
            constexpr int NCH = WS * CSTG / 8;
#pragma unroll
            for (int it = 0; it < (NCH + 255) / 256; ++it) {
                int flat = tid + it * 256;
                if (flat < NCH) {
                    int e0 = flat * 8;
                    int x = e0 / CSTG;
                    int cpos = (e0 - x * CSTG) >> 3;
                    int xs = (S == 1) ? x : ((x >> 1) + (x & 1) * WS2);
                    int dst = xs * CSTG + swz(xs, cpos);
                    long src = rowoff + (long)x * CIN + cs + cpos * 8;
                    *(int4*)&Bsh[dst] = *(const int4*)&Xh[src];
                    *(int4*)&Bsl[dst] = *(const int4*)&Xl[src];
                }
            }
            constexpr int NW = K * MT * CSTG / 8;
#pragma unroll
            for (int it = 0; it < (NW + 255) / 256; ++it) {
                int flat = tid + it * 256;
                if (flat < NW) {
                    int e0 = flat * 8;
                    int kx = e0 / (MT * CSTG);
                    int rem = e0 - kx * MT * CSTG;
                    int oc = rem / CSTG;
                    int cpos = (rem - oc * CSTG) >> 3;
                    int arow = kx * MT + oc;
                    int dst = arow * CSTG + swz(arow, cpos);
                    long src = ((long)((ky * K + kx) * CoutT + ocg * MT + oc)) * CIN + cs + cpos * 8;
                    *(int4*)&Ash[dst] = *(const int4*)&Wh[src];
                    *(int4*)&Asl[dst] = *(const int4*)&Wl[src];
                }
            }
            __syncthreads();
#pragma unroll
            for (int kx = 0; kx < K; ++kx) {
                half8 Ah[MF], Al[MF], Bh[NF], Bl[NF];
#pragma unroll
                for (int mi = 0; mi < MF; ++mi) {
                    int arow = kx * MT + wm * (MT / 2) + mi * 16 + l15;
                    int ao = arow * CSTG + swz(arow, quad);
                    Ah[mi] = *(const half8*)&Ash[ao];
                    Al[mi] = *(const half8*)&Asl[ao];
                }
#pragma unroll
                for (int ni = 0; ni < NF; ++ni) {
                    int m = wn * (NPX / 2) + ni * 16 + l15;
                    int xs = (S == 1) ? (m + kx) : (m + (kx >> 1) + (kx & 1) * WS2);
                    int bo = xs * CSTG + swz(xs, quad);
                    Bh[ni] = *(const half8*)&Bsh[bo];
                    Bl[ni] = *(const half8*)&Bsl[bo];
                }
#pragma unroll
                for (int mi = 0; mi < MF; ++mi)
#pragma unroll
                    for (int ni = 0; ni < NF; ++ni) {
                        acc[mi][ni] = __builtin_amdgcn_mfma_f32_16x16x32_f16(Ah[mi], Bh[ni], acc[mi][ni], 0, 0, 0);
                        acc[mi][ni] = __builtin_amdgcn_mfma_f32_16x16x32_f16(Al[mi], Bh[ni], acc[mi][ni], 0, 0, 0);
                        acc[mi][ni] = __builtin_amdgcn_mfma_f32_16x16x32_f16(Ah[mi], Bl[ni], acc[mi][ni], 0, 0, 0);
                    }
            }
        }
    }
#pragma unroll
    for (int ni = 0; ni < NF; ++ni) {
        const int n = ox0 + wn * (NPX / 2) + ni * 16 + l15;
#pragma unroll
        for (int mi = 0; mi < MF; ++mi) {
            const int ocf = ocg * MT + wm * (MT / 2) + mi * 16 + quad * 4;
            float4 bv = *(const float4*)&bias[ocf];
            float v0 = fmaxf(acc[mi][ni][0] + bv.x, 0.f);
            float v1 = fmaxf(acc[mi][ni][1] + bv.y, 0.f);
            float v2 = fmaxf(acc[mi][ni][2] + bv.z, 0.f);
            float v3 = fmaxf(acc[mi][ni][3] + bv.w, 0.f);
            if (WRITE_CL) {
                long o = ((long)(b * Hpn + oy + NP) * Wpn + n + NP) * CoutT + ocf;
                u16x4 hv, lv;
                ushort_t th, tl;
                split16(v0, th, tl); hv[0] = th; lv[0] = tl;
                split16(v1, th, tl); hv[1] = th; lv[1] = tl;
                split16(v2, th, tl); hv[2] = th; lv[2] = tl;
                split16(v3, th, tl); hv[3] = th; lv[3] = tl;
                *(u16x4*)&Oh[o] = hv;
                *(u16x4*)&Ol[o] = lv;
            } else {
                long o = ((long)(b * CoutT + ocf) << 12) + (oy << 6) + n;
                Ofp[o] = v0;
                Ofp[o + 4096] = v1;
                Ofp[o + 8192] = v2;
                Ofp[o + 12288] = v3;
            }
        }
    }
}

// -------- conv5 (256->1, K3 S1 P1) + relu + gate ----------
__global__ __launch_bounds__(256) void conv5_gate_k(
    const float* __restrict__ s4, const float* __restrict__ w,
    const float* __restrict__ bias, float* __restrict__ gate)
{
    const int tid = threadIdx.x;
    const int lane = tid & 63, g = tid >> 6;
    const int oy = blockIdx.x, b = blockIdx.y;
    int ixo[3], iyo[3];
#pragma unroll
    for (int k = 0; k < 3; ++k) {
        int ix = lane + k - 1; if (ix < 0) ix = -ix; if (ix >= 64) ix = 126 - ix;
        int iy = oy + k - 1; if (iy < 0) iy = -iy; if (iy >= 64) iy = 126 - iy;
        ixo[k] = ix; iyo[k] = iy << 6;
    }
    float part = 0.f;
    const float* inb = s4 + ((long)b * 256 + g * 64) * 4096;
    const float* wg = w + g * 64 * 9;
    for (int ic = 0; ic < 64; ++ic) {
        const float* inc = inb + ic * 4096;
        const float* wc = wg + ic * 9;
#pragma unroll
        for (int ky = 0; ky < 3; ++ky)
#pragma unroll
            for (int kx = 0; kx < 3; ++kx)
                part = fmaf(wc[ky * 3 + kx], inc[iyo[ky] + ixo[kx]], part);
    }
    __shared__ float red[4][64];
    red[g][lane] = part;
    __syncthreads();
    if (tid < 64) {
        float s = bias[0] + red[0][tid] + red[1][tid] + red[2][tid] + red[3][tid];
        s = fmaxf(s, 0.f);
        gate[(b << 12) + (oy << 6) + tid] = tanf(PI_F * (tanhf(s) - 0.5f));
    }
}

// ---------------- invn[b][p] = 1/sqrt(sum_c (F+1e-7)^2) ----------------
__global__ __launch_bounds__(256) void invn_k(const float* __restrict__ F, float* __restrict__ invn)
{
    const int p = blockIdx.x * 256 + threadIdx.x;
    const int b = blockIdx.y;
    const float* Fb = F + (long)b * 524288;
    float ss = 0.f;
#pragma unroll 8
    for (int c = 0; c < 128; ++c) {
        float v = Fb[c * 4096 + p] + 1e-7f;
        ss = fmaf(v, v, ss);
    }
    invn[(b << 12) + p] = 1.0f / sqrtf(ss);
}

// -------- prep: Fo16[b][c][p] = bf16(F), Ft16[b][p][c] = bf16(F^T) ---------------
__global__ __launch_bounds__(256) void prep_bf16_k(
    const float* __restrict__ F, ushort_t* __restrict__ Fo16, ushort_t* __restrict__ Ft16)
{
    __shared__ float Ls[128][65];
    const int tid = threadIdx.x;
    const int lane = tid & 63, wv = tid >> 6;
    const int p0 = blockIdx.x * 64, b = blockIdx.y;
#pragma unroll 8
    for (int cc = 0; cc < 32; ++cc) {
        int c = wv * 32 + cc;
        long idx = ((long)b * 128 + c) * 4096 + p0 + lane;
        float v = F[idx];
        Fo16[idx] = f2bf(v);
        Ls[c][lane] = v;
    }
    __syncthreads();
#pragma unroll 8
    for (int i = 0; i < 32; ++i) {
        int flat = tid + 256 * i;
        int c = flat & 127, pl_ = flat >> 7;
        Ft16[((long)b * 4096 + p0 + pl_) * 128 + c] = f2bf(Ls[c][pl_]);
    }
}

// -------- flash attention R14: double-buffered Es (1 barrier/iter), split-K=4 -----
__global__ __launch_bounds__(256) void flash_attn_k(
    const ushort_t* __restrict__ Ft16, const ushort_t* __restrict__ Fo16,
    const float* __restrict__ invn, const float* __restrict__ gate,
    float* __restrict__ Opart, float* __restrict__ lpart)
{
    __shared__ float redS[64][4];
    __shared__ ushort_t Es[2][64][72];
    const int tid = threadIdx.x, lane = tid & 63, w = tid >> 6;
    const int l15 = lane & 15, quad = lane >> 4;
    const int q0 = blockIdx.x * 64;
    const int ks = blockIdx.y, b = blockIdx.z;
    const int bp = b << 12;
    const ushort_t* Ftb = Ft16 + (long)b * 4096 * 128;
    const ushort_t* Fob = Fo16 + (long)b * 128 * 4096;

    short8 Bq[4][4];
#pragma unroll
    for (int ni = 0; ni < 4; ++ni)
#pragma unroll
        for (int cs = 0; cs < 4; ++cs)
            Bq[ni][cs] = *(const short8*)&Ftb[(long)(q0 + ni * 16 + l15) * 128 + cs * 32 + quad * 8];

    f32x4 O[2][4];
#pragma unroll
    for (int mi = 0; mi < 2; ++mi)
#pragma unroll
        for (int ni = 0; ni < 4; ++ni) O[mi][ni] = (f32x4){0.f, 0.f, 0.f, 0.f};
    float l_acc[4] = {0.f, 0.f, 0.f, 0.f};

    const int p_beg = ks * 1024;
    int buf = 0;
    for (int p0 = p_beg; p0 < p_beg + 1024; p0 += 64, buf ^= 1) {
        f32x4 Sa[4];
#pragma unroll
        for (int ni = 0; ni < 4; ++ni) Sa[ni] = (f32x4){0.f, 0.f, 0.f, 0.f};
#pragma unroll
        for (int cs = 0; cs < 4; ++cs) {
            short8 Ap = *(const short8*)&Ftb[(long)(p0 + w * 16 + l15) * 128 + cs * 32 + quad * 8];
#pragma unroll
            for (int ni = 0; ni < 4; ++ni)
                Sa[ni] = __builtin_amdgcn_mfma_f32_16x16x32_bf16(Ap, Bq[ni][cs], Sa[ni], 0, 0, 0);
        }
        float4 iv = *(const float4*)&invn[bp + p0 + w * 16 + quad * 4];
        float4 gt = *(const float4*)&gate[bp + p0 + w * 16 + quad * 4];
#pragma unroll
        for (int ni = 0; ni < 4; ++ni) {
            float e0 = __expf(fmaf(Sa[ni][0], iv.x, gt.x));
            float e1 = __expf(fmaf(Sa[ni][1], iv.y, gt.y));
            float e2 = __expf(fmaf(Sa[ni][2], iv.z, gt.z));
            float e3 = __expf(fmaf(Sa[ni][3], iv.w, gt.w));
            union { u16x4 v; __hip_bfloat162 h[2]; } u;
            u.h[0] = __float22bfloat162_rn(make_float2(e0, e1));
            u.h[1] = __float22bfloat162_rn(make_float2(e2, e3));
            *(u16x4*)&Es[buf][ni * 16 + l15][w * 16 + quad * 4] = u.v;
            l_acc[ni] += (e0 + e1) + (e2 + e3);
        }
        __syncthreads();                          // Es[buf] ready (WAR-safe: next write
                                                  // to this buf is 2 iters away, after
                                                  // every wave's O-GEMM read this iter)
#pragma unroll
        for (int ksub = 0; ksub < 2; ++ksub) {
            short8 Ac[2], Be[4];
#pragma unroll
            for (int mi = 0; mi < 2; ++mi)
                Ac[mi] = *(const short8*)&Fob[(long)(w * 32 + mi * 16 + l15) * 4096 + p0 + ksub * 32 + quad * 8];
#pragma unroll
            for (int ni = 0; ni < 4; ++ni)
                Be[ni] = *(const short8*)&Es[buf][ni * 16 + l15][ksub * 32 + quad * 8];
#pragma unroll
            for (int mi = 0; mi < 2; ++mi)
#pragma unroll
                for (int ni = 0; ni < 4; ++ni)
                    O[mi][ni] = __builtin_amdgcn_mfma_f32_16x16x32_bf16(Ac[mi], Be[ni], O[mi][ni], 0, 0, 0);
        }
    }
#pragma unroll
    for (int ni = 0; ni < 4; ++ni) {
        float lt = l_acc[ni];
        lt += __shfl_xor(lt, 16);
        lt += __shfl_xor(lt, 32);
        if (quad == 0) redS[ni * 16 + l15][w] = lt;
    }
    __syncthreads();
    if (w == 0 && quad == 0) {
#pragma unroll
        for (int ni = 0; ni < 4; ++ni) {
            int q = q0 + ni * 16 + l15;
            float4 rs = *(const float4*)&redS[ni * 16 + l15][0];
            lpart[(ks * 8 + b) * 4096 + q] = (rs.x + rs.y) + (rs.z + rs.w);
        }
    }
    float* Ob = Opart + (long)(ks * 8 + b) * 524288;
#pragma unroll
    for (int mi = 0; mi < 2; ++mi)
#pragma unroll
        for (int ni = 0; ni < 4; ++ni) {
            int c = w * 32 + mi * 16 + quad * 4;
            int q = q0 + ni * 16 + l15;
#pragma unroll
            for (int r = 0; r < 4; ++r)
                Ob[((long)(c + r) << 12) + q] = O[mi][ni][r];
        }
}

// ---------------- combiner: merge 4 split-K partials ----------------
__global__ __launch_bounds__(256) void combiner_k(
    const float* __restrict__ Opart, const float* __restrict__ lpart,
    const float* __restrict__ F, const float* __restrict__ cw,
    const float* __restrict__ cb, float* __restrict__ out)
{
    const int tid = threadIdx.x;
    const int q = blockIdx.x * 256 + tid;
    const int o0 = blockIdx.y << 4;
    const int b = blockIdx.z;
    float lsum = 0.f;
#pragma unroll
    for (int ks = 0; ks < 4; ++ks) lsum += lpart[(ks * 8 + b) * 4096 + q];
    float il = 1.0f / lsum;
    const float* Fb = F + (long)b * 524288 + q;
    float acc[16];
#pragma unroll
    for (int j = 0; j < 16; ++j) acc[j] = cb[o0 + j];
    for (int c = 0; c < 128; ++c) {
        float a = 0.f;
#pragma unroll
        for (int ks = 0; ks < 4; ++ks)
            a += Opart[(long)(ks * 8 + b) * 524288 + (long)c * 4096 + q];
        a *= il;
        float f = Fb[(long)c * 4096];
#pragma unroll
        for (int j = 0; j < 16; ++j) {
            acc[j] = fmaf(cw[(o0 + j) * 256 + c], a, acc[j]);
            acc[j] = fmaf(cw[(o0 + j) * 256 + 128 + c], f, acc[j]);
        }
    }
#pragma unroll
    for (int j = 0; j < 16; ++j)
        out[((long)(b * 128 + o0 + j) << 12) + q] = acc[j];
}

// =====================================================================================
extern "C" void kernel_launch(void* const* d_in, const int* in_sizes, int n_in,
                              void* d_out, int out_size, void* d_ws, size_t ws_size,
                              hipStream_t stream)
{
    const float* F     = (const float*)d_in[0];
    const float* imgs  = (const float*)d_in[1];
    const float* masks = (const float*)d_in[2];
    const float* gw1 = (const float*)d_in[3];  const float* gb1 = (const float*)d_in[4];
    const float* gw2 = (const float*)d_in[5];  const float* gb2 = (const float*)d_in[6];
    const float* gw3 = (const float*)d_in[7];  const float* gb3 = (const float*)d_in[8];
    const float* gw4 = (const float*)d_in[9];  const float* gb4 = (const float*)d_in[10];
    const float* gw5 = (const float*)d_in[11]; const float* gb5 = (const float*)d_in[12];
    const float* cw  = (const float*)d_in[13]; const float* cb  = (const float*)d_in[14];
    float* out = (float*)d_out;

    // ---- workspace layout (float offsets), ~150 MB ----
    float* W = (float*)d_ws;
    ushort_t* Xcl2h = (ushort_t*)(W);                 // [8][260][260][32] fp16
    ushort_t* Xcl2l = (ushort_t*)(W + 8652800);
    ushort_t* Xcl4h = (ushort_t*)(W);                 // [8][130][130][128] fp16
    ushort_t* Xcl4l = (ushort_t*)(W + 8652800);
    float*    Opart = W;                              // [4][8][128][4096] f32 (16.78M fl)
    float*    lpart = W + 16777216;                   // [4][8][4096] (131k fl)
    ushort_t* Xcl3h = (ushort_t*)(W + 17305600);      // [8][132][132][64] fp16
    ushort_t* Xcl3l = (ushort_t*)(W + 21766144);
    ushort_t* Fo16  = (ushort_t*)(W + 17305600);      // [8][128][4096] bf16 (after conv3)
    float*    s4   = W + 26226688;                    // [8][256][64][64] f32
    ushort_t* Ft16 = (ushort_t*)(W + 30420992);       // [8][4096][128] bf16 (after conv5)
    ushort_t* W2h = (ushort_t*)(W + 34615296);
    ushort_t* W2l = (ushort_t*)(W + 34640896);
    ushort_t* W3h = (ushort_t*)(W + 34666496);
    ushort_t* W3l = (ushort_t*)(W + 34768896);
    ushort_t* W4h = (ushort_t*)(W + 34871296);
    ushort_t* W4l = (ushort_t*)(W + 35018752);
    float* gate = W + 35166208;
    float* invn = W + 35198976;
    ushort_t* Xinh = (ushort_t*)(W + 35231744);       // [8][262][262][4] fp16 + slack
    ushort_t* Xinl = (ushort_t*)(W + 36330080);
    ushort_t* W1h  = (ushort_t*)(W + 37428416);       // [7][32][32] fp16
    ushort_t* W1l  = (ushort_t*)(W + 37432000);

    // ---- weight transforms + conv1 input prep ----
    transform_w_k<<<dim3(200),  256, 0, stream>>>(gw2, W2h, W2l, 64, 32, 25);
    transform_w_k<<<dim3(800),  256, 0, stream>>>(gw3, W3h, W3l, 128, 64, 25);
    transform_w_k<<<dim3(1152), 256, 0, stream>>>(gw4, W4h, W4l, 256, 128, 9);
    transform_w1_k<<<dim3(28), 256, 0, stream>>>(gw1, W1h, W1l);
    prep_in_k<<<dim3(262, 8), 256, 0, stream>>>(imgs, masks, Xinh, Xinl);

    // ---- conv stack ----
    conv1_mfma_k<<<dim3(4, 256, 8), 256, 0, stream>>>(Xinh, Xinl, W1h, W1l, gb1, Xcl2h, Xcl2l);
    pad_cl_k<<<dim3(260, 8), 256, 0, stream>>>(Xcl2h, Xcl2l, 260, 260, 2, 32, 256, 256);
    // conv2: wave 32x64 (NPX=128), 2 blocks/CU
    conv_mfma_k<5, 2, 32, 32, 64, 128, true><<<dim3(1, 128, 8), 256, 0, stream>>>(
        Xcl2h, Xcl2l, W2h, W2l, gb2, 260, 260, 64, Xcl3h, Xcl3l, 132, 132, 2, nullptr);
    pad_cl_k<<<dim3(132, 8), 256, 0, stream>>>(Xcl3h, Xcl3l, 132, 132, 2, 64, 128, 128);
    // conv3: R12 config (MT=64, NPX=128, 2 blocks/CU) -- R13's MT=128 was 1 block/CU, regressed
    conv_mfma_k<5, 1, 64, 32, 64, 128, true><<<dim3(1, 128, 16), 256, 0, stream>>>(
        Xcl3h, Xcl3l, W3h, W3l, gb3, 132, 132, 128, Xcl4h, Xcl4l, 130, 130, 1, nullptr);
    pad_cl_k<<<dim3(130, 8), 256, 0, stream>>>(Xcl4h, Xcl4l, 130, 130, 1, 128, 128, 128);
    // conv4: MT=128 NOC=2, wave 64x32, 2 blocks/CU
    conv_mfma_k<3, 2, 128, 32, 128, 64, false><<<dim3(1, 64, 16), 256, 0, stream>>>(
        Xcl4h, Xcl4l, W4h, W4l, gb4, 130, 130, 256, nullptr, nullptr, 0, 0, 0, s4);
    conv5_gate_k<<<dim3(64, 8), 256, 0, stream>>>(s4, gw5, gb5, gate);

    // ---- attention ----
    invn_k<<<dim3(16, 8), 256, 0, stream>>>(F, invn);
    prep_bf16_k<<<dim3(64, 8), 256, 0, stream>>>(F, Fo16, Ft16);
    flash_attn_k<<<dim3(64, 4, 8), 256, 0, stream>>>(Ft16, Fo16, invn, gate, Opart, lpart);
    combiner_k<<<dim3(16, 8, 8), 256, 0, stream>>>(Opart, lpart, F, cw, cb, out);
}

// Round 15
// 662.163 us; speedup vs baseline: 1.2410x; 1.1549x over previous
//
#include <hip/hip_runtime.h>
#include <hip/hip_bf16.h>
#include <hip/hip_fp16.h>
#include <math.h>

// GatedAttention R15: 2-term split conv GEMMs. Weights stay split-fp16 (Ah+Al);
// activations are fp16-hi ONLY (dropped Bl operand + Ah*Bl MFMA). Cuts conv LDS
// reads 12->8 per kx (the measured bound: LDS-read-BW, MfmaUtil 38%), kills all
// low-activation buffers/writes, conv3 LDS 57.8->49.4 KB (3 blocks/CU).
// Activation-rounding error analysis: delta_s/s ~1e-3 -> delta_gate ~0.012 ->
// absmax expected ~0.010-0.016 (threshold 0.032). Flash/combiner = R14.

#define PI_F 3.1415926f

typedef __attribute__((ext_vector_type(8))) short short8;
typedef __attribute__((ext_vector_type(4))) float f32x4;
typedef _Float16 half8 __attribute__((ext_vector_type(8)));
typedef __attribute__((ext_vector_type(4))) unsigned short u16x4;
typedef unsigned short ushort_t;

__device__ __forceinline__ ushort_t f2bf(float x) {
    unsigned u = __float_as_uint(x);
    unsigned r = (u + 0x7FFFu + ((u >> 16) & 1u)) >> 16;
    return (ushort_t)r;
}
__device__ __forceinline__ void split16(float x, ushort_t& h, ushort_t& l) {
    __half hh = __float2half(x);
    h = __half_as_ushort(hh);
    l = __half_as_ushort(__float2half(x - __half2float(hh)));
}
__device__ __forceinline__ ushort_t f2h(float x) {
    return __half_as_ushort(__float2half(x));
}
__device__ __forceinline__ int swz(int r, int c) {
    return ((c ^ r ^ (r >> 2)) & 3) << 3;
}

// ---------------- weight transform: OIHW fp32 -> [ky*kx][oc][ic] fp16 hi/lo --------
__global__ __launch_bounds__(256) void transform_w_k(
    const float* __restrict__ w, ushort_t* __restrict__ Wh, ushort_t* __restrict__ Wl,
    int Cout, int Cin, int KK)
{
    int idx = blockIdx.x * 256 + threadIdx.x;
    int N = Cout * Cin * KK;
    if (idx >= N) return;
    int oc = idx / (Cin * KK);
    int rem = idx - oc * (Cin * KK);
    int ic = rem / KK;
    int t = rem - ic * KK;
    float v = w[idx];
    long dst = ((long)t * Cout + oc) * Cin + ic;
    split16(v, Wh[dst], Wl[dst]);
}

// ------- conv1 weight transform: [32][4][7][7] -> [7 ky][32 oc][32 k=kx*4+ic] ------
__global__ __launch_bounds__(256) void transform_w1_k(
    const float* __restrict__ w, ushort_t* __restrict__ Wh, ushort_t* __restrict__ Wl)
{
    int idx = blockIdx.x * 256 + threadIdx.x;
    if (idx >= 7 * 32 * 32) return;
    int ky = idx / 1024;
    int rem = idx - ky * 1024;
    int oc = rem >> 5;
    int k = rem & 31;
    float v = 0.f;
    if (k < 28) {
        int kx = k >> 2, ic = k & 3;
        v = w[((oc * 4 + ic) * 7 + ky) * 7 + kx];
    }
    split16(v, Wh[idx], Wl[idx]);
}

// ------- prep conv1 input: reflect-pad(3) -> channel-last [8][262][262][4] fp16 h --
__global__ __launch_bounds__(256) void prep_in_k(
    const float* __restrict__ imgs, const float* __restrict__ masks,
    ushort_t* __restrict__ Xh)
{
    const int iy = blockIdx.x, b = blockIdx.y;
    int sy = iy - 3; if (sy < 0) sy = -sy; if (sy >= 256) sy = 510 - sy;
    const int rb = sy << 8;
    const float* i0 = imgs + (long)b * 3 * 65536;
    const float* mk = masks + (long)b * 65536;
    for (int x = threadIdx.x; x < 262; x += 256) {
        int sx = x - 3; if (sx < 0) sx = -sx; if (sx >= 256) sx = 510 - sx;
        u16x4 hv;
        hv[0] = f2h(i0[rb + sx]);
        hv[1] = f2h(i0[65536 + rb + sx]);
        hv[2] = f2h(i0[131072 + rb + sx]);
        hv[3] = f2h(mk[rb + sx]);
        long o = ((long)(b * 262 + iy) * 262 + x) * 4;
        *(u16x4*)&Xh[o] = hv;
    }
}

// ------- conv1 MFMA (2-term): 32 oc x 64 px per block -----------
__global__ __launch_bounds__(256) void conv1_mfma_k(
    const ushort_t* __restrict__ Xinh,
    const ushort_t* __restrict__ W1h, const ushort_t* __restrict__ W1l,
    const float* __restrict__ bias, ushort_t* __restrict__ Oh)
{
    const int tid = threadIdx.x, lane = tid & 63, wid = tid >> 6;
    const int wm = wid & 1, wn = wid >> 1, l15 = lane & 15, quad = lane >> 4;
    const int ox0 = blockIdx.x * 64;
    const int oy = blockIdx.y, b = blockIdx.z;
    f32x4 acc[2];
    acc[0] = (f32x4){0.f, 0.f, 0.f, 0.f};
    acc[1] = (f32x4){0.f, 0.f, 0.f, 0.f};
#pragma unroll
    for (int ky = 0; ky < 7; ++ky) {
        long wo = (long)(ky * 32 + wm * 16 + l15) * 32 + quad * 8;
        half8 Ah = *(const half8*)&W1h[wo];
        half8 Al = *(const half8*)&W1l[wo];
        long xrow = ((long)(b * 262 + oy + ky) * 262 + ox0) * 4;
#pragma unroll
        for (int ni = 0; ni < 2; ++ni) {
            long xo = xrow + (wn * 32 + ni * 16 + l15) * 4 + quad * 8;
            half8 Bh = *(const half8*)&Xinh[xo];
            acc[ni] = __builtin_amdgcn_mfma_f32_16x16x32_f16(Ah, Bh, acc[ni], 0, 0, 0);
            acc[ni] = __builtin_amdgcn_mfma_f32_16x16x32_f16(Al, Bh, acc[ni], 0, 0, 0);
        }
    }
    const int ocf = wm * 16 + quad * 4;
    float4 bv = *(const float4*)&bias[ocf];
#pragma unroll
    for (int ni = 0; ni < 2; ++ni) {
        int n = ox0 + wn * 32 + ni * 16 + l15;
        u16x4 hv;
        hv[0] = f2h(fmaxf(acc[ni][0] + bv.x, 0.f));
        hv[1] = f2h(fmaxf(acc[ni][1] + bv.y, 0.f));
        hv[2] = f2h(fmaxf(acc[ni][2] + bv.z, 0.f));
        hv[3] = f2h(fmaxf(acc[ni][3] + bv.w, 0.f));
        long o = ((long)(b * 260 + oy + 2) * 260 + n + 2) * 32 + ocf;
        *(u16x4*)&Oh[o] = hv;
    }
}

// ------- pad-fill for channel-last reflect-padded h-only buffers ----
__global__ __launch_bounds__(256) void pad_cl_k(
    ushort_t* __restrict__ Xh, int Hp, int Wp, int PAD, int C, int H, int W)
{
    const int iy = blockIdx.x, b = blockIdx.y;
    int t = iy - PAD; if (t < 0) t = -t; if (t >= H) t = 2 * H - 2 - t;
    const int iys = t + PAD;
    const long rowd = ((long)(b * Hp + iy) * Wp) * C;
    const long rows = ((long)(b * Hp + iys) * Wp) * C;
    const int nch = Wp * (C >> 3);
    for (int idx = threadIdx.x; idx < nch; idx += 256) {
        int x = idx / (C >> 3);
        int cg = (idx - x * (C >> 3)) << 3;
        int t2 = x - PAD; if (t2 < 0) t2 = -t2; if (t2 >= W) t2 = 2 * W - 2 - t2;
        int xs = t2 + PAD;
        if (xs == x && iys == iy) continue;
        *(int4*)&Xh[rowd + (long)x * C + cg] = *(const int4*)&Xh[rows + (long)xs * C + cg];
    }
}

// ------- MFMA conv (2-term split), swizzled LDS, de-interleave for S=2 ----
template<int K, int S, int CIN, int CSTG, int MT, int NPX, bool WRITE_CL>
__global__ __launch_bounds__(256, 2) void conv_mfma_k(
    const ushort_t* __restrict__ Xh,
    const ushort_t* __restrict__ Wh, const ushort_t* __restrict__ Wl,
    const float* __restrict__ bias,
    int Hp, int Wp, int CoutT,
    ushort_t* __restrict__ Oh, int Hpn, int Wpn, int NP,
    float* __restrict__ Ofp)
{
    constexpr int WS = (NPX - 1) * S + K;
    constexpr int WS2 = (WS + 1) / 2;
    constexpr int MF = MT / 32;
    constexpr int NF = NPX / 32;
    __shared__ ushort_t Bsh[WS * CSTG];
    __shared__ ushort_t Ash[K * MT * CSTG];
    __shared__ ushort_t Asl[K * MT * CSTG];
    const int tid = threadIdx.x, lane = tid & 63, wid = tid >> 6;
    const int wm = wid & 1, wn = wid >> 1, l15 = lane & 15, quad = lane >> 4;
    const int bx = blockIdx.x, oy = blockIdx.y;
    const int NOC = CoutT / MT;
    const int ocg = blockIdx.z % NOC, b = blockIdx.z / NOC;
    const int ox0 = bx * NPX;

    f32x4 acc[MF][NF];
#pragma unroll
    for (int mi = 0; mi < MF; ++mi)
#pragma unroll
        for (int ni = 0; ni < NF; ++ni) acc[mi][ni] = (f32x4){0.f, 0.f, 0.f, 0.f};

#pragma unroll
    for (int ky = 0; ky < K; ++ky) {
        const long rowoff = ((long)(b * Hp + oy * S + ky) * Wp + ox0 * S) * CIN;
        for (int cs = 0; cs < CIN; cs += CSTG) {
            __syncthreads();
            constexpr int NCH = WS * CSTG / 8;
#pragma unroll
            for (int it = 0; it < (NCH + 255) / 256; ++it) {
                int flat = tid + it * 256;
                if (flat < NCH) {
                    int e0 = flat * 8;
                    int x = e0 / CSTG;
                    int cpos = (e0 - x * CSTG) >> 3;
                    int xs = (S == 1) ? x : ((x >> 1) + (x & 1) * WS2);
                    *(int4*)&Bsh[xs * CSTG + swz(xs, cpos)] =
                        *(const int4*)&Xh[rowoff + (long)x * CIN + cs + cpos * 8];
                }
            }
            constexpr int NW = K * MT * CSTG / 8;
#pragma unroll
            for (int it = 0; it < (NW + 255) / 256; ++it) {
                int flat = tid + it * 256;
                if (flat < NW) {
                    int e0 = flat * 8;
                    int kx = e0 / (MT * CSTG);
                    int rem = e0 - kx * MT * CSTG;
                    int oc = rem / CSTG;
                    int cpos = (rem - oc * CSTG) >> 3;
                    int arow = kx * MT + oc;
                    int dst = arow * CSTG + swz(arow, cpos);
                    long src = ((long)((ky * K + kx) * CoutT + ocg * MT + oc)) * CIN + cs + cpos * 8;
                    *(int4*)&Ash[dst] = *(const int4*)&Wh[src];
                    *(int4*)&Asl[dst] = *(const int4*)&Wl[src];
                }
            }
            __syncthreads();
#pragma unroll
            for (int kx = 0; kx < K; ++kx) {
                half8 Ah[MF], Al[MF], Bh[NF];
#pragma unroll
                for (int mi = 0; mi < MF; ++mi) {
                    int arow = kx * MT + wm * (MT / 2) + mi * 16 + l15;
                    int ao = arow * CSTG + swz(arow, quad);
                    Ah[mi] = *(const half8*)&Ash[ao];
                    Al[mi] = *(const half8*)&Asl[ao];
                }
#pragma unroll
                for (int ni = 0; ni < NF; ++ni) {
                    int m = wn * (NPX / 2) + ni * 16 + l15;
                    int xs = (S == 1) ? (m + kx) : (m + (kx >> 1) + (kx & 1) * WS2);
                    Bh[ni] = *(const half8*)&Bsh[xs * CSTG + swz(xs, quad)];
                }
#pragma unroll
                for (int mi = 0; mi < MF; ++mi)
#pragma unroll
                    for (int ni = 0; ni < NF; ++ni) {
                        acc[mi][ni] = __builtin_amdgcn_mfma_f32_16x16x32_f16(Ah[mi], Bh[ni], acc[mi][ni], 0, 0, 0);
                        acc[mi][ni] = __builtin_amdgcn_mfma_f32_16x16x32_f16(Al[mi], Bh[ni], acc[mi][ni], 0, 0, 0);
                    }
            }
        }
    }
#pragma unroll
    for (int ni = 0; ni < NF; ++ni) {
        const int n = ox0 + wn * (NPX / 2) + ni * 16 + l15;
#pragma unroll
        for (int mi = 0; mi < MF; ++mi) {
            const int ocf = ocg * MT + wm * (MT / 2) + mi * 16 + quad * 4;
            float4 bv = *(const float4*)&bias[ocf];
            float v0 = fmaxf(acc[mi][ni][0] + bv.x, 0.f);
            float v1 = fmaxf(acc[mi][ni][1] + bv.y, 0.f);
            float v2 = fmaxf(acc[mi][ni][2] + bv.z, 0.f);
            float v3 = fmaxf(acc[mi][ni][3] + bv.w, 0.f);
            if (WRITE_CL) {
                long o = ((long)(b * Hpn + oy + NP) * Wpn + n + NP) * CoutT + ocf;
                u16x4 hv;
                hv[0] = f2h(v0); hv[1] = f2h(v1); hv[2] = f2h(v2); hv[3] = f2h(v3);
                *(u16x4*)&Oh[o] = hv;
            } else {
                long o = ((long)(b * CoutT + ocf) << 12) + (oy << 6) + n;
                Ofp[o] = v0;
                Ofp[o + 4096] = v1;
                Ofp[o + 8192] = v2;
                Ofp[o + 12288] = v3;
            }
        }
    }
}

// -------- conv5 (256->1, K3 S1 P1) + relu + gate ----------
__global__ __launch_bounds__(256) void conv5_gate_k(
    const float* __restrict__ s4, const float* __restrict__ w,
    const float* __restrict__ bias, float* __restrict__ gate)
{
    const int tid = threadIdx.x;
    const int lane = tid & 63, g = tid >> 6;
    const int oy = blockIdx.x, b = blockIdx.y;
    int ixo[3], iyo[3];
#pragma unroll
    for (int k = 0; k < 3; ++k) {
        int ix = lane + k - 1; if (ix < 0) ix = -ix; if (ix >= 64) ix = 126 - ix;
        int iy = oy + k - 1; if (iy < 0) iy = -iy; if (iy >= 64) iy = 126 - iy;
        ixo[k] = ix; iyo[k] = iy << 6;
    }
    float part = 0.f;
    const float* inb = s4 + ((long)b * 256 + g * 64) * 4096;
    const float* wg = w + g * 64 * 9;
    for (int ic = 0; ic < 64; ++ic) {
        const float* inc = inb + ic * 4096;
        const float* wc = wg + ic * 9;
#pragma unroll
        for (int ky = 0; ky < 3; ++ky)
#pragma unroll
            for (int kx = 0; kx < 3; ++kx)
                part = fmaf(wc[ky * 3 + kx], inc[iyo[ky] + ixo[kx]], part);
    }
    __shared__ float red[4][64];
    red[g][lane] = part;
    __syncthreads();
    if (tid < 64) {
        float s = bias[0] + red[0][tid] + red[1][tid] + red[2][tid] + red[3][tid];
        s = fmaxf(s, 0.f);
        gate[(b << 12) + (oy << 6) + tid] = tanf(PI_F * (tanhf(s) - 0.5f));
    }
}

// ---------------- invn[b][p] = 1/sqrt(sum_c (F+1e-7)^2) ----------------
__global__ __launch_bounds__(256) void invn_k(const float* __restrict__ F, float* __restrict__ invn)
{
    const int p = blockIdx.x * 256 + threadIdx.x;
    const int b = blockIdx.y;
    const float* Fb = F + (long)b * 524288;
    float ss = 0.f;
#pragma unroll 8
    for (int c = 0; c < 128; ++c) {
        float v = Fb[c * 4096 + p] + 1e-7f;
        ss = fmaf(v, v, ss);
    }
    invn[(b << 12) + p] = 1.0f / sqrtf(ss);
}

// -------- prep: Fo16[b][c][p] = bf16(F), Ft16[b][p][c] = bf16(F^T) ---------------
__global__ __launch_bounds__(256) void prep_bf16_k(
    const float* __restrict__ F, ushort_t* __restrict__ Fo16, ushort_t* __restrict__ Ft16)
{
    __shared__ float Ls[128][65];
    const int tid = threadIdx.x;
    const int lane = tid & 63, wv = tid >> 6;
    const int p0 = blockIdx.x * 64, b = blockIdx.y;
#pragma unroll 8
    for (int cc = 0; cc < 32; ++cc) {
        int c = wv * 32 + cc;
        long idx = ((long)b * 128 + c) * 4096 + p0 + lane;
        float v = F[idx];
        Fo16[idx] = f2bf(v);
        Ls[c][lane] = v;
    }
    __syncthreads();
#pragma unroll 8
    for (int i = 0; i < 32; ++i) {
        int flat = tid + 256 * i;
        int c = flat & 127, pl_ = flat >> 7;
        Ft16[((long)b * 4096 + p0 + pl_) * 128 + c] = f2bf(Ls[c][pl_]);
    }
}

// -------- flash attention (R14): dbuf Es, 1 barrier/iter, split-K=4 ---------------
__global__ __launch_bounds__(256) void flash_attn_k(
    const ushort_t* __restrict__ Ft16, const ushort_t* __restrict__ Fo16,
    const float* __restrict__ invn, const float* __restrict__ gate,
    float* __restrict__ Opart, float* __restrict__ lpart)
{
    __shared__ float redS[64][4];
    __shared__ ushort_t Es[2][64][72];
    const int tid = threadIdx.x, lane = tid & 63, w = tid >> 6;
    const int l15 = lane & 15, quad = lane >> 4;
    const int q0 = blockIdx.x * 64;
    const int ks = blockIdx.y, b = blockIdx.z;
    const int bp = b << 12;
    const ushort_t* Ftb = Ft16 + (long)b * 4096 * 128;
    const ushort_t* Fob = Fo16 + (long)b * 128 * 4096;

    short8 Bq[4][4];
#pragma unroll
    for (int ni = 0; ni < 4; ++ni)
#pragma unroll
        for (int cs = 0; cs < 4; ++cs)
            Bq[ni][cs] = *(const short8*)&Ftb[(long)(q0 + ni * 16 + l15) * 128 + cs * 32 + quad * 8];

    f32x4 O[2][4];
#pragma unroll
    for (int mi = 0; mi < 2; ++mi)
#pragma unroll
        for (int ni = 0; ni < 4; ++ni) O[mi][ni] = (f32x4){0.f, 0.f, 0.f, 0.f};
    float l_acc[4] = {0.f, 0.f, 0.f, 0.f};

    const int p_beg = ks * 1024;
    int buf = 0;
    for (int p0 = p_beg; p0 < p_beg + 1024; p0 += 64, buf ^= 1) {
        f32x4 Sa[4];
#pragma unroll
        for (int ni = 0; ni < 4; ++ni) Sa[ni] = (f32x4){0.f, 0.f, 0.f, 0.f};
#pragma unroll
        for (int cs = 0; cs < 4; ++cs) {
            short8 Ap = *(const short8*)&Ftb[(long)(p0 + w * 16 + l15) * 128 + cs * 32 + quad * 8];
#pragma unroll
            for (int ni = 0; ni < 4; ++ni)
                Sa[ni] = __builtin_amdgcn_mfma_f32_16x16x32_bf16(Ap, Bq[ni][cs], Sa[ni], 0, 0, 0);
        }
        float4 iv = *(const float4*)&invn[bp + p0 + w * 16 + quad * 4];
        float4 gt = *(const float4*)&gate[bp + p0 + w * 16 + quad * 4];
#pragma unroll
        for (int ni = 0; ni < 4; ++ni) {
            float e0 = __expf(fmaf(Sa[ni][0], iv.x, gt.x));
            float e1 = __expf(fmaf(Sa[ni][1], iv.y, gt.y));
            float e2 = __expf(fmaf(Sa[ni][2], iv.z, gt.z));
            float e3 = __expf(fmaf(Sa[ni][3], iv.w, gt.w));
            union { u16x4 v; __hip_bfloat162 h[2]; } u;
            u.h[0] = __float22bfloat162_rn(make_float2(e0, e1));
            u.h[1] = __float22bfloat162_rn(make_float2(e2, e3));
            *(u16x4*)&Es[buf][ni * 16 + l15][w * 16 + quad * 4] = u.v;
            l_acc[ni] += (e0 + e1) + (e2 + e3);
        }
        __syncthreads();
#pragma unroll
        for (int ksub = 0; ksub < 2; ++ksub) {
            short8 Ac[2], Be[4];
#pragma unroll
            for (int mi = 0; mi < 2; ++mi)
                Ac[mi] = *(const short8*)&Fob[(long)(w * 32 + mi * 16 + l15) * 4096 + p0 + ksub * 32 + quad * 8];
#pragma unroll
            for (int ni = 0; ni < 4; ++ni)
                Be[ni] = *(const short8*)&Es[buf][ni * 16 + l15][ksub * 32 + quad * 8];
#pragma unroll
            for (int mi = 0; mi < 2; ++mi)
#pragma unroll
                for (int ni = 0; ni < 4; ++ni)
                    O[mi][ni] = __builtin_amdgcn_mfma_f32_16x16x32_bf16(Ac[mi], Be[ni], O[mi][ni], 0, 0, 0);
        }
    }
#pragma unroll
    for (int ni = 0; ni < 4; ++ni) {
        float lt = l_acc[ni];
        lt += __shfl_xor(lt, 16);
        lt += __shfl_xor(lt, 32);
        if (quad == 0) redS[ni * 16 + l15][w] = lt;
    }
    __syncthreads();
    if (w == 0 && quad == 0) {
#pragma unroll
        for (int ni = 0; ni < 4; ++ni) {
            int q = q0 + ni * 16 + l15;
            float4 rs = *(const float4*)&redS[ni * 16 + l15][0];
            lpart[(ks * 8 + b) * 4096 + q] = (rs.x + rs.y) + (rs.z + rs.w);
        }
    }
    float* Ob = Opart + (long)(ks * 8 + b) * 524288;
#pragma unroll
    for (int mi = 0; mi < 2; ++mi)
#pragma unroll
        for (int ni = 0; ni < 4; ++ni) {
            int c = w * 32 + mi * 16 + quad * 4;
            int q = q0 + ni * 16 + l15;
#pragma unroll
            for (int r = 0; r < 4; ++r)
                Ob[((long)(c + r) << 12) + q] = O[mi][ni][r];
        }
}

// ---------------- combiner: merge 4 split-K partials ----------------
__global__ __launch_bounds__(256) void combiner_k(
    const float* __restrict__ Opart, const float* __restrict__ lpart,
    const float* __restrict__ F, const float* __restrict__ cw,
    const float* __restrict__ cb, float* __restrict__ out)
{
    const int tid = threadIdx.x;
    const int q = blockIdx.x * 256 + tid;
    const int o0 = blockIdx.y << 4;
    const int b = blockIdx.z;
    float lsum = 0.f;
#pragma unroll
    for (int ks = 0; ks < 4; ++ks) lsum += lpart[(ks * 8 + b) * 4096 + q];
    float il = 1.0f / lsum;
    const float* Fb = F + (long)b * 524288 + q;
    float acc[16];
#pragma unroll
    for (int j = 0; j < 16; ++j) acc[j] = cb[o0 + j];
    for (int c = 0; c < 128; ++c) {
        float a = 0.f;
#pragma unroll
        for (int ks = 0; ks < 4; ++ks)
            a += Opart[(long)(ks * 8 + b) * 524288 + (long)c * 4096 + q];
        a *= il;
        float f = Fb[(long)c * 4096];
#pragma unroll
        for (int j = 0; j < 16; ++j) {
            acc[j] = fmaf(cw[(o0 + j) * 256 + c], a, acc[j]);
            acc[j] = fmaf(cw[(o0 + j) * 256 + 128 + c], f, acc[j]);
        }
    }
#pragma unroll
    for (int j = 0; j < 16; ++j)
        out[((long)(b * 128 + o0 + j) << 12) + q] = acc[j];
}

// =====================================================================================
extern "C" void kernel_launch(void* const* d_in, const int* in_sizes, int n_in,
                              void* d_out, int out_size, void* d_ws, size_t ws_size,
                              hipStream_t stream)
{
    const float* F     = (const float*)d_in[0];
    const float* imgs  = (const float*)d_in[1];
    const float* masks = (const float*)d_in[2];
    const float* gw1 = (const float*)d_in[3];  const float* gb1 = (const float*)d_in[4];
    const float* gw2 = (const float*)d_in[5];  const float* gb2 = (const float*)d_in[6];
    const float* gw3 = (const float*)d_in[7];  const float* gb3 = (const float*)d_in[8];
    const float* gw4 = (const float*)d_in[9];  const float* gb4 = (const float*)d_in[10];
    const float* gw5 = (const float*)d_in[11]; const float* gb5 = (const float*)d_in[12];
    const float* cw  = (const float*)d_in[13]; const float* cb  = (const float*)d_in[14];
    float* out = (float*)d_out;

    // ---- workspace layout (float offsets), ~150 MB ----
    float* W = (float*)d_ws;
    ushort_t* Xcl2h = (ushort_t*)(W);                 // [8][260][260][32] fp16 h
    ushort_t* Xcl4h = (ushort_t*)(W);                 // [8][130][130][128] fp16 h
    float*    Opart = W;                              // [4][8][128][4096] f32
    float*    lpart = W + 16777216;                   // [4][8][4096]
    ushort_t* Xcl3h = (ushort_t*)(W + 17305600);      // [8][132][132][64] fp16 h
    ushort_t* Fo16  = (ushort_t*)(W + 17305600);      // [8][128][4096] bf16 (after conv3)
    float*    s4   = W + 26226688;                    // [8][256][64][64] f32
    ushort_t* Ft16 = (ushort_t*)(W + 30420992);       // [8][4096][128] bf16 (after conv5)
    ushort_t* W2h = (ushort_t*)(W + 34615296);
    ushort_t* W2l = (ushort_t*)(W + 34640896);
    ushort_t* W3h = (ushort_t*)(W + 34666496);
    ushort_t* W3l = (ushort_t*)(W + 34768896);
    ushort_t* W4h = (ushort_t*)(W + 34871296);
    ushort_t* W4l = (ushort_t*)(W + 35018752);
    float* gate = W + 35166208;
    float* invn = W + 35198976;
    ushort_t* Xinh = (ushort_t*)(W + 35231744);       // [8][262][262][4] fp16 h + slack
    ushort_t* W1h  = (ushort_t*)(W + 37428416);       // [7][32][32] fp16
    ushort_t* W1l  = (ushort_t*)(W + 37432000);

    // ---- weight transforms + conv1 input prep ----
    transform_w_k<<<dim3(200),  256, 0, stream>>>(gw2, W2h, W2l, 64, 32, 25);
    transform_w_k<<<dim3(800),  256, 0, stream>>>(gw3, W3h, W3l, 128, 64, 25);
    transform_w_k<<<dim3(1152), 256, 0, stream>>>(gw4, W4h, W4l, 256, 128, 9);
    transform_w1_k<<<dim3(28), 256, 0, stream>>>(gw1, W1h, W1l);
    prep_in_k<<<dim3(262, 8), 256, 0, stream>>>(imgs, masks, Xinh);

    // ---- conv stack (2-term split: weights h+l, activations h only) ----
    conv1_mfma_k<<<dim3(4, 256, 8), 256, 0, stream>>>(Xinh, W1h, W1l, gb1, Xcl2h);
    pad_cl_k<<<dim3(260, 8), 256, 0, stream>>>(Xcl2h, 260, 260, 2, 32, 256, 256);
    conv_mfma_k<5, 2, 32, 32, 64, 128, true><<<dim3(1, 128, 8), 256, 0, stream>>>(
        Xcl2h, W2h, W2l, gb2, 260, 260, 64, Xcl3h, 132, 132, 2, nullptr);
    pad_cl_k<<<dim3(132, 8), 256, 0, stream>>>(Xcl3h, 132, 132, 2, 64, 128, 128);
    conv_mfma_k<5, 1, 64, 32, 64, 128, true><<<dim3(1, 128, 16), 256, 0, stream>>>(
        Xcl3h, W3h, W3l, gb3, 132, 132, 128, Xcl4h, 130, 130, 1, nullptr);
    pad_cl_k<<<dim3(130, 8), 256, 0, stream>>>(Xcl4h, 130, 130, 1, 128, 128, 128);
    conv_mfma_k<3, 2, 128, 32, 128, 64, false><<<dim3(1, 64, 16), 256, 0, stream>>>(
        Xcl4h, W4h, W4l, gb4, 130, 130, 256, nullptr, 0, 0, 0, s4);
    conv5_gate_k<<<dim3(64, 8), 256, 0, stream>>>(s4, gw5, gb5, gate);

    // ---- attention ----
    invn_k<<<dim3(16, 8), 256, 0, stream>>>(F, invn);
    prep_bf16_k<<<dim3(64, 8), 256, 0, stream>>>(F, Fo16, Ft16);
    flash_attn_k<<<dim3(64, 4, 8), 256, 0, stream>>>(Ft16, Fo16, invn, gate, Opart, lpart);
    combiner_k<<<dim3(16, 8, 8), 256, 0, stream>>>(Opart, lpart, F, cw, cb, out);
}